// Round 1
// baseline (192.844 us; speedup 1.0000x reference)
//
#include <hip/hip_runtime.h>

#define D     4096
#define NH    32
#define HD    128
#define TT    8192
#define SINKN 4
#define NC    64
#define CS    (TT / NC)   // 128 keys per chunk
#define ICH   32          // i-chunks for split-K GEMV
#define IROWS (D / ICH)   // 128 rows per chunk

// ---------------- K1: q/k/v = x @ {Wq,Wk,Wv}, split-K partials ----------------
// grid = 3 mats * 4 colblocks(1024) * ICH, block = 256
__global__ void qkv_partial(const float* __restrict__ x,
                            const float* __restrict__ Wq,
                            const float* __restrict__ Wk,
                            const float* __restrict__ Wv,
                            float* __restrict__ partA) {
    int bid = blockIdx.x;
    int mat = bid / (4 * ICH);
    int rem = bid % (4 * ICH);
    int jb  = rem / ICH;
    int ic  = rem % ICH;
    const float* Wm = (mat == 0) ? Wq : (mat == 1) ? Wk : Wv;
    int tid = threadIdx.x;
    int j0  = jb * 1024 + tid * 4;
    int i0  = ic * IROWS;
    __shared__ float xs[IROWS];
    if (tid < IROWS) xs[tid] = x[i0 + tid];
    __syncthreads();
    float4 acc = {0.f, 0.f, 0.f, 0.f};
    const float* Wp = Wm + (size_t)i0 * D + j0;
    for (int i = 0; i < IROWS; ++i) {
        float4 w = *(const float4*)Wp;
        float xv = xs[i];
        acc.x += xv * w.x; acc.y += xv * w.y;
        acc.z += xv * w.z; acc.w += xv * w.w;
        Wp += D;
    }
    *(float4*)(partA + ((size_t)(mat * ICH + ic)) * D + j0) = acc;
}

// grid = 3*D/256, block = 256. qkv = ws base (q|k_new|v_new consecutive).
__global__ void qkv_reduce(const float* __restrict__ partA,
                           float* __restrict__ qkv,
                           float* __restrict__ newK,
                           float* __restrict__ newV) {
    int idx = blockIdx.x * 256 + threadIdx.x;   // 0 .. 3*D
    int mat = idx / D;
    int j   = idx % D;
    const float* p = partA + (size_t)mat * ICH * D + j;
    float s = 0.f;
    #pragma unroll
    for (int ic = 0; ic < ICH; ++ic) s += p[(size_t)ic * D];
    qkv[idx] = s;
    if (mat == 1) {            // k_new -> new cache slot TT-1
        int h = j / HD, d = j % HD;
        newK[((size_t)h * TT + (TT - 1)) * HD + d] = s;
    } else if (mat == 2) {     // v_new
        int h = j / HD, d = j % HD;
        newV[((size_t)h * TT + (TT - 1)) * HD + d] = s;
    }
}

// ---------------- K2: attention partials + fused sink-evict shift ----------------
// grid = NH*NC, block = 256 (4 waves). Each block: head h, keys [c*CS, c*CS+CS)
__global__ void attn_chunk(const float* __restrict__ q,
                           const float* __restrict__ K,
                           const float* __restrict__ V,
                           float* __restrict__ newK,
                           float* __restrict__ newV,
                           float* __restrict__ partB) {
    int bid = blockIdx.x;
    int h = bid / NC;
    int c = bid % NC;
    int t0 = c * CS;
    int tid  = threadIdx.x;
    int wave = tid >> 6;
    int lane = tid & 63;
    __shared__ float qs[HD];
    __shared__ float sc[CS];
    __shared__ float ml[2];
    __shared__ float ctx4[4][HD];
    if (tid < HD) qs[tid] = q[h * HD + tid];
    __syncthreads();
    float q0 = qs[2 * lane], q1 = qs[2 * lane + 1];
    const float inv_sqrt_d = 0.08838834764831845f; // 1/sqrt(128)

    const float* Kh = K    + (size_t)h * TT * HD;
    float*      nKh = newK + (size_t)h * TT * HD;
    // pass 1: scores + shifted K write (row t -> t-1 for t>4; drop t==4)
    for (int kk = 0; kk < CS / 4; ++kk) {
        int t = t0 + kk * 4 + wave;
        const float2 kv = *(const float2*)(Kh + (size_t)t * HD + 2 * lane);
        float p = q0 * kv.x + q1 * kv.y;
        #pragma unroll
        for (int off = 32; off; off >>= 1) p += __shfl_xor(p, off, 64);
        if (lane == 0) sc[t - t0] = p * inv_sqrt_d;
        if (t != SINKN) {
            int dst = (t < SINKN) ? t : t - 1;
            *(float2*)(nKh + (size_t)dst * HD + 2 * lane) = kv;
        }
    }
    __syncthreads();
    // chunk-local softmax (wave 0): m, exp-weights back into sc, l
    if (wave == 0) {
        float s0 = sc[lane], s1 = sc[lane + 64];
        float m = fmaxf(s0, s1);
        #pragma unroll
        for (int off = 32; off; off >>= 1) m = fmaxf(m, __shfl_xor(m, off, 64));
        float w0 = __expf(s0 - m), w1 = __expf(s1 - m);
        sc[lane] = w0; sc[lane + 64] = w1;
        float l = w0 + w1;
        #pragma unroll
        for (int off = 32; off; off >>= 1) l += __shfl_xor(l, off, 64);
        if (lane == 0) { ml[0] = m; ml[1] = l; }
    }
    __syncthreads();
    // pass 2: weighted V sum + shifted V write
    const float* Vh = V    + (size_t)h * TT * HD;
    float*      nVh = newV + (size_t)h * TT * HD;
    float a0 = 0.f, a1 = 0.f;
    for (int kk = 0; kk < CS / 4; ++kk) {
        int t = t0 + kk * 4 + wave;
        const float2 vv = *(const float2*)(Vh + (size_t)t * HD + 2 * lane);
        float w = sc[t - t0];
        a0 += w * vv.x; a1 += w * vv.y;
        if (t != SINKN) {
            int dst = (t < SINKN) ? t : t - 1;
            *(float2*)(nVh + (size_t)dst * HD + 2 * lane) = vv;
        }
    }
    ctx4[wave][2 * lane]     = a0;
    ctx4[wave][2 * lane + 1] = a1;
    __syncthreads();
    float* pb = partB + ((size_t)h * NC + c) * (HD + 2);
    if (tid < HD)
        pb[2 + tid] = ctx4[0][tid] + ctx4[1][tid] + ctx4[2][tid] + ctx4[3][tid];
    if (tid == 0) { pb[0] = ml[0]; pb[1] = ml[1]; }
}

// ---------------- K3: per-head flash combine + new-token term ----------------
// grid = NH, block = HD
__global__ void attn_combine(const float* __restrict__ q,
                             const float* __restrict__ knew,
                             const float* __restrict__ vnew,
                             const float* __restrict__ partB,
                             float* __restrict__ ctx) {
    int h = blockIdx.x;
    int tid = threadIdx.x;   // 0..127
    __shared__ float red[HD];
    __shared__ float marr[NC], larr[NC];
    red[tid] = q[h * HD + tid] * knew[h * HD + tid];
    __syncthreads();
    for (int s = 64; s > 0; s >>= 1) {
        if (tid < s) red[tid] += red[tid + s];
        __syncthreads();
    }
    float s_new = red[0] * 0.08838834764831845f;
    const float* pb = partB + (size_t)h * NC * (HD + 2);
    if (tid < NC) {
        marr[tid] = pb[(size_t)tid * (HD + 2)];
        larr[tid] = pb[(size_t)tid * (HD + 2) + 1];
    }
    __syncthreads();
    float M = s_new;
    for (int c = 0; c < NC; ++c) M = fmaxf(M, marr[c]);
    float wn = __expf(s_new - M);
    float L = wn;
    for (int c = 0; c < NC; ++c) L += larr[c] * __expf(marr[c] - M);
    float acc = wn * vnew[h * HD + tid];
    for (int c = 0; c < NC; ++c)
        acc += __expf(marr[c] - M) * pb[(size_t)c * (HD + 2) + 2 + tid];
    ctx[h * HD + tid] = acc / L;
}

// ---------------- K4: out = ctx @ Wo, split-K ----------------
// grid = 4*ICH, block = 256
__global__ void out_partial(const float* __restrict__ ctx,
                            const float* __restrict__ Wo,
                            float* __restrict__ partA) {
    int bid = blockIdx.x;
    int jb = bid / ICH, ic = bid % ICH;
    int tid = threadIdx.x;
    int j0 = jb * 1024 + tid * 4;
    int i0 = ic * IROWS;
    __shared__ float xs[IROWS];
    if (tid < IROWS) xs[tid] = ctx[i0 + tid];
    __syncthreads();
    float4 acc = {0.f, 0.f, 0.f, 0.f};
    const float* Wp = Wo + (size_t)i0 * D + j0;
    for (int i = 0; i < IROWS; ++i) {
        float4 w = *(const float4*)Wp;
        float xv = xs[i];
        acc.x += xv * w.x; acc.y += xv * w.y;
        acc.z += xv * w.z; acc.w += xv * w.w;
        Wp += D;
    }
    *(float4*)(partA + (size_t)ic * D + j0) = acc;
}

// grid = D/256, block = 256
__global__ void out_reduce(const float* __restrict__ partA,
                           float* __restrict__ out) {
    int j = blockIdx.x * 256 + threadIdx.x;
    float s = 0.f;
    #pragma unroll
    for (int ic = 0; ic < ICH; ++ic) s += partA[(size_t)ic * D + j];
    out[j] = s;
}

extern "C" void kernel_launch(void* const* d_in, const int* in_sizes, int n_in,
                              void* d_out, int out_size, void* d_ws, size_t ws_size,
                              hipStream_t stream) {
    const float* x  = (const float*)d_in[0];
    const float* cK = (const float*)d_in[1];
    const float* cV = (const float*)d_in[2];
    const float* Wq = (const float*)d_in[3];
    const float* Wk = (const float*)d_in[4];
    const float* Wv = (const float*)d_in[5];
    const float* Wo = (const float*)d_in[6];

    float* out  = (float*)d_out;
    float* newK = out + D;
    float* newV = newK + (size_t)NH * TT * HD;

    float* ws    = (float*)d_ws;
    float* q     = ws;                 // D
    float* kn    = ws + D;             // D
    float* vn    = ws + 2 * D;         // D
    float* ctx   = ws + 3 * D;         // D
    float* partA = ws + 4 * D;         // 3*ICH*D (reused by out_partial)
    float* partB = partA + 3 * ICH * D;// NH*NC*(HD+2)

    qkv_partial <<<3 * 4 * ICH, 256, 0, stream>>>(x, Wq, Wk, Wv, partA);
    qkv_reduce  <<<3 * D / 256, 256, 0, stream>>>(partA, q, newK, newV);
    attn_chunk  <<<NH * NC,     256, 0, stream>>>(q, cK, cV, newK, newV, partB);
    attn_combine<<<NH,          HD,  0, stream>>>(q, kn, vn, partB, ctx);
    out_partial <<<4 * ICH,     256, 0, stream>>>(ctx, Wo, partA);
    out_reduce  <<<D / 256,     256, 0, stream>>>(partA, out);
}

// Round 2
// 189.890 us; speedup vs baseline: 1.0156x; 1.0156x over previous
//
#include <hip/hip_runtime.h>

#define D     4096
#define NH    32
#define HD    128
#define TT    8192
#define SINKN 4
#define NC    64
#define CS    (TT / NC)   // 128 keys per chunk
#define ICH   32          // K-split for qkv GEMV
#define ICHO  64          // K-split for out GEMV

// ---------------- K1: q/k/v partials = x @ {Wq,Wk,Wv} ----------------
// grid = 3 * 8 jb * 32 ic = 768 blocks (exactly 3/CU), block = 128
__global__ void qkv_partial(const float* __restrict__ x,
                            const float* __restrict__ Wq,
                            const float* __restrict__ Wk,
                            const float* __restrict__ Wv,
                            float* __restrict__ partA) {
    int bid = blockIdx.x;
    int mat = bid / 256;
    int rem = bid % 256;
    int jb  = rem >> 5;          // 0..7
    int ic  = rem & 31;          // 0..31
    const float* Wm = (mat == 0) ? Wq : (mat == 1) ? Wk : Wv;
    int tid = threadIdx.x;       // 0..127
    int j0  = jb * 512 + tid * 4;
    int i0  = ic * 128;
    __shared__ float xs[128];
    xs[tid] = x[i0 + tid];
    __syncthreads();
    float4 acc = {0.f, 0.f, 0.f, 0.f};
    const float* Wp = Wm + (size_t)i0 * D + j0;
    #pragma unroll 8
    for (int i = 0; i < 128; ++i) {
        float4 w = *(const float4*)Wp;
        float xv = xs[i];
        acc.x += xv * w.x; acc.y += xv * w.y;
        acc.z += xv * w.z; acc.w += xv * w.w;
        Wp += D;
    }
    *(float4*)(partA + (size_t)(mat * ICH + ic) * D + j0) = acc;
}

// ---------------- K2: attention partials + fused q-reduce + evict shift ----------------
// grid = NH*NC = 2048 (8/CU), block = 256 (4 waves)
__global__ void attn_chunk(const float* __restrict__ partA,
                           const float* __restrict__ K,
                           const float* __restrict__ V,
                           float* __restrict__ newK,
                           float* __restrict__ newV,
                           float* __restrict__ partB) {
    int bid = blockIdx.x;
    int h = bid / NC;
    int c = bid % NC;
    int t0 = c * CS;
    int tid  = threadIdx.x;
    int wave = tid >> 6;
    int lane = tid & 63;
    int l31  = lane & 31;
    int half = lane >> 5;

    __shared__ float qs[HD];
    __shared__ float sc[CS];
    __shared__ float ml[2];
    __shared__ float ctx8[8][HD];

    // fused q-reduce for this head: q[d] = sum_ic partA[ic*D + h*HD + d]
    {
        int d  = tid & 127;
        int hh = tid >> 7;   // 0/1
        const float* p = partA + (size_t)(hh * 16) * D + (size_t)h * HD + d;
        float s = 0.f;
        #pragma unroll
        for (int ic = 0; ic < 16; ++ic) s += p[(size_t)ic * D];
        ctx8[hh][d] = s;     // scratch use
    }
    __syncthreads();
    if (tid < HD) qs[tid] = ctx8[0][tid] + ctx8[1][tid];
    __syncthreads();

    float4 qv = *(const float4*)(qs + 4 * l31);
    const float scale = 0.08838834764831845f; // 1/sqrt(128)

    const float* Kh = K    + (size_t)h * TT * HD;
    float*      nKh = newK + (size_t)h * TT * HD;
    // pass 1: scores + shifted K write (row r -> r-1 for r>4; drop r==4)
    for (int kk = 0; kk < 16; ++kk) {
        int r = t0 + kk * 8 + wave * 2 + half;
        float4 kv = *(const float4*)(Kh + (size_t)r * HD + 4 * l31);
        float p = qv.x * kv.x + qv.y * kv.y + qv.z * kv.z + qv.w * kv.w;
        p += __shfl_xor(p, 16, 64);
        p += __shfl_xor(p, 8, 64);
        p += __shfl_xor(p, 4, 64);
        p += __shfl_xor(p, 2, 64);
        p += __shfl_xor(p, 1, 64);
        if (l31 == 0) sc[r - t0] = p * scale;
        if (r != SINKN) {
            int dst = (r < SINKN) ? r : r - 1;
            *(float4*)(nKh + (size_t)dst * HD + 4 * l31) = kv;
        }
    }
    __syncthreads();
    // chunk-local softmax (wave 0)
    if (wave == 0) {
        float s0 = sc[lane], s1 = sc[lane + 64];
        float m = fmaxf(s0, s1);
        #pragma unroll
        for (int off = 32; off; off >>= 1) m = fmaxf(m, __shfl_xor(m, off, 64));
        float w0 = __expf(s0 - m), w1 = __expf(s1 - m);
        sc[lane] = w0; sc[lane + 64] = w1;
        float l = w0 + w1;
        #pragma unroll
        for (int off = 32; off; off >>= 1) l += __shfl_xor(l, off, 64);
        if (lane == 0) { ml[0] = m; ml[1] = l; }
    }
    __syncthreads();
    // pass 2: weighted V sum + shifted V write
    const float* Vh = V    + (size_t)h * TT * HD;
    float*      nVh = newV + (size_t)h * TT * HD;
    float a0 = 0.f, a1 = 0.f, a2 = 0.f, a3 = 0.f;
    for (int kk = 0; kk < 16; ++kk) {
        int r = t0 + kk * 8 + wave * 2 + half;
        float4 vv = *(const float4*)(Vh + (size_t)r * HD + 4 * l31);
        float w = sc[r - t0];
        a0 += w * vv.x; a1 += w * vv.y; a2 += w * vv.z; a3 += w * vv.w;
        if (r != SINKN) {
            int dst = (r < SINKN) ? r : r - 1;
            *(float4*)(nVh + (size_t)dst * HD + 4 * l31) = vv;
        }
    }
    int g = wave * 2 + half;
    ctx8[g][4 * l31 + 0] = a0;
    ctx8[g][4 * l31 + 1] = a1;
    ctx8[g][4 * l31 + 2] = a2;
    ctx8[g][4 * l31 + 3] = a3;
    __syncthreads();
    float* pb = partB + ((size_t)h * NC + c) * (HD + 2);
    if (tid < HD) {
        float s = 0.f;
        #pragma unroll
        for (int gg = 0; gg < 8; ++gg) s += ctx8[gg][tid];
        pb[2 + tid] = s;
    }
    if (tid == 0) { pb[0] = ml[0]; pb[1] = ml[1]; }
}

// ---------------- K3: per-head combine + k_new/v_new reduce + slot 8191 ----------------
// grid = NH, block = HD
__global__ void attn_combine(const float* __restrict__ partA,
                             const float* __restrict__ partB,
                             float* __restrict__ newK,
                             float* __restrict__ newV,
                             float* __restrict__ ctx) {
    int h = blockIdx.x;
    int tid = threadIdx.x;   // 0..127
    float qd = 0.f, kd = 0.f, vd = 0.f;
    const float* pq = partA + (size_t)h * HD + tid;
    #pragma unroll
    for (int ic = 0; ic < ICH; ++ic) {
        qd += pq[(size_t)ic * D];
        kd += pq[(size_t)(ICH + ic) * D];
        vd += pq[(size_t)(2 * ICH + ic) * D];
    }
    newK[((size_t)h * TT + (TT - 1)) * HD + tid] = kd;
    newV[((size_t)h * TT + (TT - 1)) * HD + tid] = vd;

    __shared__ float red[HD];
    __shared__ float marr[NC], larr[NC], earr[NC];
    red[tid] = qd * kd;
    __syncthreads();
    for (int s = 64; s > 0; s >>= 1) {
        if (tid < s) red[tid] += red[tid + s];
        __syncthreads();
    }
    float s_new = red[0] * 0.08838834764831845f;
    const float* pb = partB + (size_t)h * NC * (HD + 2);
    if (tid < NC) {
        marr[tid] = pb[(size_t)tid * (HD + 2)];
        larr[tid] = pb[(size_t)tid * (HD + 2) + 1];
    }
    __syncthreads();
    float M = s_new;
    for (int c = 0; c < NC; ++c) M = fmaxf(M, marr[c]);
    if (tid < NC) earr[tid] = __expf(marr[tid] - M);
    __syncthreads();
    float wn = __expf(s_new - M);
    float L = wn;
    for (int c = 0; c < NC; ++c) L += larr[c] * earr[c];
    float acc = wn * vd;
    for (int c = 0; c < NC; ++c)
        acc += earr[c] * pb[(size_t)c * (HD + 2) + 2 + tid];
    ctx[h * HD + tid] = acc / L;
}

// ---------------- K4: out = ctx @ Wo partials ----------------
// grid = 8 jb * 64 ic = 512 blocks (2/CU), block = 128
__global__ void out_partial(const float* __restrict__ ctx,
                            const float* __restrict__ Wo,
                            float* __restrict__ partC) {
    int bid = blockIdx.x;
    int jb = bid >> 6;       // 0..7
    int ic = bid & 63;       // 0..63
    int tid = threadIdx.x;   // 0..127
    int j0 = jb * 512 + tid * 4;
    int i0 = ic * 64;
    __shared__ float xs[64];
    if (tid < 64) xs[tid] = ctx[i0 + tid];
    __syncthreads();
    float4 acc = {0.f, 0.f, 0.f, 0.f};
    const float* Wp = Wo + (size_t)i0 * D + j0;
    #pragma unroll 8
    for (int i = 0; i < 64; ++i) {
        float4 w = *(const float4*)Wp;
        float xv = xs[i];
        acc.x += xv * w.x; acc.y += xv * w.y;
        acc.z += xv * w.z; acc.w += xv * w.w;
        Wp += D;
    }
    *(float4*)(partC + (size_t)ic * D + j0) = acc;
}

// grid = D/256 = 16, block = 256
__global__ void out_reduce(const float* __restrict__ partC,
                           float* __restrict__ out) {
    int j = blockIdx.x * 256 + threadIdx.x;
    float s = 0.f;
    #pragma unroll
    for (int ic = 0; ic < ICHO; ++ic) s += partC[(size_t)ic * D + j];
    out[j] = s;
}

extern "C" void kernel_launch(void* const* d_in, const int* in_sizes, int n_in,
                              void* d_out, int out_size, void* d_ws, size_t ws_size,
                              hipStream_t stream) {
    const float* x  = (const float*)d_in[0];
    const float* cK = (const float*)d_in[1];
    const float* cV = (const float*)d_in[2];
    const float* Wq = (const float*)d_in[3];
    const float* Wk = (const float*)d_in[4];
    const float* Wv = (const float*)d_in[5];
    const float* Wo = (const float*)d_in[6];

    float* out  = (float*)d_out;
    float* newK = out + D;
    float* newV = newK + (size_t)NH * TT * HD;

    float* ws    = (float*)d_ws;
    float* partA = ws;                               // 3*ICH*D floats (out_partial reuses: ICHO*D <= 3*ICH*D)
    float* partB = partA + 3 * ICH * D;              // NH*NC*(HD+2)
    float* ctx   = partB + NH * NC * (HD + 2);       // D

    qkv_partial <<<768,  128, 0, stream>>>(x, Wq, Wk, Wv, partA);
    attn_chunk  <<<NH * NC, 256, 0, stream>>>(partA, cK, cV, newK, newV, partB);
    attn_combine<<<NH,   HD,  0, stream>>>(partA, partB, newK, newV, ctx);
    out_partial <<<512,  128, 0, stream>>>(ctx, Wo, partA);
    out_reduce  <<<D / 256, 256, 0, stream>>>(partA, out);
}

// Round 3
// 182.369 us; speedup vs baseline: 1.0574x; 1.0412x over previous
//
#include <hip/hip_runtime.h>

#define D     4096
#define NH    32
#define HD    128
#define TT    8192
#define SINKN 4
#define NC    64
#define CS    128         // keys per chunk
#define ICH   64          // K-split chunks for qkv GEMV (64 rows each)
#define PBSTR (HD + 2)

// ---------------- K1: q/k/v partials = x @ {Wq,Wk,Wv}; zero out[0:4096] ----------------
// grid = 3 * 4 jb * 64 ic = 768 blocks, block = 256 (12 waves/CU)
__global__ __launch_bounds__(256) void qkv_partial(
        const float* __restrict__ x,
        const float* __restrict__ Wq,
        const float* __restrict__ Wk,
        const float* __restrict__ Wv,
        float* __restrict__ partA,
        float* __restrict__ out) {
    int bid = blockIdx.x;
    int tid = threadIdx.x;
    if (bid < 16) out[bid * 256 + tid] = 0.f;   // init for K3 atomics
    int mat = bid >> 8;          // 0..2
    int rem = bid & 255;
    int jb  = rem >> 6;          // 0..3
    int ic  = rem & 63;          // 0..63
    const float* Wm = (mat == 0) ? Wq : (mat == 1) ? Wk : Wv;
    int j0 = jb * 1024 + tid * 4;
    int i0 = ic * 64;
    __shared__ float xs[64];
    if (tid < 64) xs[tid] = x[i0 + tid];
    __syncthreads();
    float4 acc = {0.f, 0.f, 0.f, 0.f};
    const float* Wp = Wm + (size_t)i0 * D + j0;
    #pragma unroll 16
    for (int i = 0; i < 64; ++i) {
        float4 w = *(const float4*)Wp;
        float xv = xs[i];
        acc.x += xv * w.x; acc.y += xv * w.y;
        acc.z += xv * w.z; acc.w += xv * w.w;
        Wp += D;
    }
    *(float4*)(partA + (size_t)(mat * ICH + ic) * D + j0) = acc;
}

// ---------------- K2: attention partials + q-reduce + evict shift + new-token entry ----------------
// grid = NH*NC = 2048 (8 blocks/CU), block = 256
__global__ __launch_bounds__(256) void attn_chunk(
        const float* __restrict__ partA,
        const float* __restrict__ K,
        const float* __restrict__ V,
        float* __restrict__ newK,
        float* __restrict__ newV,
        float* __restrict__ partB) {
    int bid = blockIdx.x;
    int h = bid >> 6;
    int c = bid & 63;
    int t0 = c * CS;
    int tid  = threadIdx.x;
    int wave = tid >> 6;
    int lane = tid & 63;
    int l31  = lane & 31;
    int half = lane >> 5;

    __shared__ float qs[HD];
    __shared__ float sc[CS];
    __shared__ float ml[2];
    __shared__ float ctx8[8][HD];

    // fused q-reduce: q[d] = sum over 64 partial rows
    {
        int d  = tid & 127;
        int hh = tid >> 7;   // 0/1 -> halves of the 64 chunks
        const float* p = partA + (size_t)(hh * 32) * D + (size_t)h * HD + d;
        float s = 0.f;
        #pragma unroll
        for (int i = 0; i < 32; ++i) s += p[(size_t)i * D];
        ctx8[hh][d] = s;
    }
    __syncthreads();
    if (tid < HD) qs[tid] = ctx8[0][tid] + ctx8[1][tid];
    __syncthreads();

    float4 qv = *(const float4*)(qs + 4 * l31);
    const float scale = 0.08838834764831845f; // 1/sqrt(128)

    const float* Kh = K    + (size_t)h * TT * HD;
    float*      nKh = newK + (size_t)h * TT * HD;
    // pass 1: scores + shifted K write (row r -> r-1 for r>4; drop r==4)
    for (int kk = 0; kk < 16; ++kk) {
        int r = t0 + kk * 8 + wave * 2 + half;
        float4 kv = *(const float4*)(Kh + (size_t)r * HD + 4 * l31);
        float p = qv.x * kv.x + qv.y * kv.y + qv.z * kv.z + qv.w * kv.w;
        p += __shfl_xor(p, 16, 64);
        p += __shfl_xor(p, 8, 64);
        p += __shfl_xor(p, 4, 64);
        p += __shfl_xor(p, 2, 64);
        p += __shfl_xor(p, 1, 64);
        if (l31 == 0) sc[r - t0] = p * scale;
        if (r != SINKN) {
            int dst = (r < SINKN) ? r : r - 1;
            *(float4*)(nKh + (size_t)dst * HD + 4 * l31) = kv;
        }
    }
    __syncthreads();
    // chunk-local softmax (wave 0)
    if (wave == 0) {
        float s0 = sc[lane], s1 = sc[lane + 64];
        float m = fmaxf(s0, s1);
        #pragma unroll
        for (int off = 32; off; off >>= 1) m = fmaxf(m, __shfl_xor(m, off, 64));
        float w0 = __expf(s0 - m), w1 = __expf(s1 - m);
        sc[lane] = w0; sc[lane + 64] = w1;
        float l = w0 + w1;
        #pragma unroll
        for (int off = 32; off; off >>= 1) l += __shfl_xor(l, off, 64);
        if (lane == 0) { ml[0] = m; ml[1] = l; }
    }
    __syncthreads();
    // pass 2: weighted V sum + shifted V write
    const float* Vh = V    + (size_t)h * TT * HD;
    float*      nVh = newV + (size_t)h * TT * HD;
    float a0 = 0.f, a1 = 0.f, a2 = 0.f, a3 = 0.f;
    for (int kk = 0; kk < 16; ++kk) {
        int r = t0 + kk * 8 + wave * 2 + half;
        float4 vv = *(const float4*)(Vh + (size_t)r * HD + 4 * l31);
        float w = sc[r - t0];
        a0 += w * vv.x; a1 += w * vv.y; a2 += w * vv.z; a3 += w * vv.w;
        if (r != SINKN) {
            int dst = (r < SINKN) ? r : r - 1;
            *(float4*)(nVh + (size_t)dst * HD + 4 * l31) = vv;
        }
    }
    int g = wave * 2 + half;
    ctx8[g][4 * l31 + 0] = a0;
    ctx8[g][4 * l31 + 1] = a1;
    ctx8[g][4 * l31 + 2] = a2;
    ctx8[g][4 * l31 + 3] = a3;
    __syncthreads();
    float* pbE = partB + ((size_t)h * (NC + 1) + c) * PBSTR;
    if (tid < HD) {
        float s = 0.f;
        #pragma unroll
        for (int gg = 0; gg < 8; ++gg) s += ctx8[gg][tid];
        pbE[2 + tid] = s;
    }
    if (tid == 0) { pbE[0] = ml[0]; pbE[1] = ml[1]; }

    // c==0 blocks: reduce k_new/v_new, write cache slot TT-1, emit 65th entry
    if (c == 0) {
        float kd = 0.f, vd = 0.f;
        if (tid < HD) {
            const float* pk = partA + (size_t)(ICH) * D + (size_t)h * HD + tid;
            const float* pv = partA + (size_t)(2 * ICH) * D + (size_t)h * HD + tid;
            #pragma unroll
            for (int i = 0; i < ICH; ++i) {
                kd += pk[(size_t)i * D];
                vd += pv[(size_t)i * D];
            }
            newK[((size_t)h * TT + (TT - 1)) * HD + tid] = kd;
            newV[((size_t)h * TT + (TT - 1)) * HD + tid] = vd;
        }
        __syncthreads();             // ctx8 reads above are done; safe to reuse
        if (tid < HD) ctx8[0][tid] = qs[tid] * kd;
        __syncthreads();
        float* pbN = partB + ((size_t)h * (NC + 1) + NC) * PBSTR;
        if (tid < 64) {
            float s = ctx8[0][tid] + ctx8[0][tid + 64];
            #pragma unroll
            for (int off = 32; off; off >>= 1) s += __shfl_xor(s, off, 64);
            if (tid == 0) { pbN[0] = s * scale; pbN[1] = 1.0f; }
        }
        if (tid < HD) pbN[2 + tid] = vd;
    }
}

// ---------------- K3: fused combine-slice + out GEMV with atomic reduce ----------------
// grid = 8 jb * 64 ic = 512 blocks, block = 128
__global__ __launch_bounds__(128) void out_fused(
        const float* __restrict__ partB,
        const float* __restrict__ Wo,
        float* __restrict__ out) {
    int bid = blockIdx.x;
    int jb = bid >> 6;       // 0..7
    int ic = bid & 63;       // 0..63
    int tid = threadIdx.x;   // 0..127
    int h  = ic >> 1;        // rows [ic*64, ic*64+64) sit in one head
    int d0 = (ic & 1) * 64;

    __shared__ float marr[NC + 1], larr[NC + 1], wgt[NC + 1];
    __shared__ float ctx[64];
    __shared__ float Ls;

    const float* pb = partB + (size_t)h * (NC + 1) * PBSTR;
    if (tid <= NC) {
        marr[tid] = pb[tid * PBSTR];
        larr[tid] = pb[tid * PBSTR + 1];
    }
    __syncthreads();
    float M = marr[0];
    #pragma unroll
    for (int cc = 1; cc <= NC; ++cc) M = fmaxf(M, marr[cc]);
    if (tid <= NC) wgt[tid] = __expf(marr[tid] - M);
    __syncthreads();
    if (tid < 64) {
        float s = wgt[tid] * larr[tid] + ((tid == 0) ? wgt[NC] * larr[NC] : 0.f);
        #pragma unroll
        for (int off = 32; off; off >>= 1) s += __shfl_xor(s, off, 64);
        if (tid == 0) Ls = s;
    }
    __syncthreads();
    if (tid < 64) {
        const float* pc = pb + 2 + d0 + tid;
        float acc = 0.f;
        #pragma unroll
        for (int cc = 0; cc <= NC; ++cc) acc += wgt[cc] * pc[cc * PBSTR];
        ctx[tid] = acc / Ls;
    }
    __syncthreads();

    int j0 = jb * 512 + tid * 4;
    float4 acc = {0.f, 0.f, 0.f, 0.f};
    const float* Wp = Wo + (size_t)(ic * 64) * D + j0;
    #pragma unroll 16
    for (int i = 0; i < 64; ++i) {
        float4 w = *(const float4*)Wp;
        float xv = ctx[i];
        acc.x += xv * w.x; acc.y += xv * w.y;
        acc.z += xv * w.z; acc.w += xv * w.w;
        Wp += D;
    }
    atomicAdd(&out[j0 + 0], acc.x);
    atomicAdd(&out[j0 + 1], acc.y);
    atomicAdd(&out[j0 + 2], acc.z);
    atomicAdd(&out[j0 + 3], acc.w);
}

extern "C" void kernel_launch(void* const* d_in, const int* in_sizes, int n_in,
                              void* d_out, int out_size, void* d_ws, size_t ws_size,
                              hipStream_t stream) {
    const float* x  = (const float*)d_in[0];
    const float* cK = (const float*)d_in[1];
    const float* cV = (const float*)d_in[2];
    const float* Wq = (const float*)d_in[3];
    const float* Wk = (const float*)d_in[4];
    const float* Wv = (const float*)d_in[5];
    const float* Wo = (const float*)d_in[6];

    float* out  = (float*)d_out;
    float* newK = out + D;
    float* newV = newK + (size_t)NH * TT * HD;

    float* ws    = (float*)d_ws;
    float* partA = ws;                       // 3*ICH*D floats = 3 MB
    float* partB = partA + 3 * ICH * D;      // NH*(NC+1)*PBSTR

    qkv_partial<<<768,     256, 0, stream>>>(x, Wq, Wk, Wv, partA, out);
    attn_chunk <<<NH * NC, 256, 0, stream>>>(partA, cK, cV, newK, newV, partB);
    out_fused  <<<512,     128, 0, stream>>>(partB, Wo, out);
}